// Round 4
// baseline (403.977 us; speedup 1.0000x reference)
//
#include <hip/hip_runtime.h>
#include <hip/hip_bf16.h>
#include <stdint.h>

// ======================================================================
// EMSA fused pipeline. Device dtype (bf16 vs f32) detected at runtime.
// Algebra:
//  * S_i = Q_i K_i^T /8 computed ONCE per input head (9.7 GF, not the
//    77 GF of the folded-K' variant); head-mix tw done in-register.
//  * softmax row-sums are 1  =>  instance-norm mean = 1/256 exactly
//  * Dev = P - 1/256; var = mean(Dev^2); out = (Dev@V)*rsqrt(var+eps)
//  * tb cancels in softmax (constant per row) -> dropped
//  * instance-norm scale folded into per-batch pre-scaled Wo^T
//  * 1/sqrt(dk)=1/8 folded into WqT and bq
// ======================================================================

typedef __bf16 bf16;
typedef __bf16 bf16x8 __attribute__((ext_vector_type(8)));
typedef float  f32x4  __attribute__((ext_vector_type(4)));

#define LDS_AS  __attribute__((address_space(3)))
#define GLOB_AS __attribute__((address_space(1)))

__device__ __forceinline__ void gload_lds16(const bf16* g, void* l) {
    __builtin_amdgcn_global_load_lds((const GLOB_AS void*)g, (LDS_AS void*)l, 16, 0, 0);
}

// ---------------- constants ----------------
#define NB   16
#define NQ   2304
#define DD   512
#define NHH  8
#define NKV  256

// workspace layout (bytes)
constexpr size_t OFF_WQT = 0;
constexpr size_t OFF_WKT = OFF_WQT + 512*512*2;
constexpr size_t OFF_WVT = OFF_WKT + 512*512*2;
constexpr size_t OFF_WOT = OFF_WVT + 512*512*2;
constexpr size_t OFF_X   = OFF_WOT + 512*512*2;                       // (16,256,512) bf16; later aliased by WoTp
constexpr size_t OFF_KT  = OFF_X  + (size_t)NB*NKV*DD*2;              // (16,256,512) bf16; aliased by WoTp tail
constexpr size_t OFF_VT  = OFF_KT + (size_t)NB*NKV*DD*2;              // (16,8,64,256) bf16
constexpr size_t OFF_QF  = OFF_VT + (size_t)NB*NHH*64*NKV*2;          // (16,2304,512) bf16
constexpr size_t OFF_U   = OFF_QF + (size_t)NB*NQ*DD*2;               // (16,2304,512) bf16 (also canonical queries)
constexpr size_t OFF_SS  = OFF_U  + (size_t)NB*NQ*DD*2;               // 128 f32
constexpr size_t OFF_SM  = OFF_SS + 512;                              // small canonical bf16
constexpr size_t OFF_FLG = OFF_SM + 24064;                            // int flag
constexpr size_t OFF_WOTP = OFF_X;                                    // (16,512,512) bf16 = 8 MB, aliases X+KT (dead by then)

// small-region element offsets
#define SM_BQ  0
#define SM_BK  512
#define SM_BV  1024
#define SM_BO  1536
#define SM_SRW 2048
#define SM_SRB 10240
#define SM_LNG 10752
#define SM_LNB 11264
#define SM_TW  11776

// ---------------- dtype detection ----------------
__global__ __launch_bounds__(64) void detect_dtype(const uint32_t* __restrict__ q,
                                                   int* __restrict__ flag)
{
    int t = threadIdx.x;
    int cnt = 0;
    #pragma unroll
    for (int i = 0; i < 8; i++) {
        uint32_t w = q[t*8 + i];
        int e = (w >> 7) & 0xFF;
        cnt += (e >= 100 && e <= 150) ? 1 : 0;
    }
    #pragma unroll
    for (int m = 1; m < 64; m <<= 1) cnt += __shfl_xor(cnt, m);
    if (t == 0) *flag = (cnt >= 384) ? 0 : 1;   // 0=bf16, 1=f32
}

// ---------------- input conversion ----------------
__global__ __launch_bounds__(256) void convert_q(const void* __restrict__ in,
                                                 bf16* __restrict__ out,
                                                 const int* __restrict__ flag)
{
    int idx = blockIdx.x * 256 + threadIdx.x;
    bf16x8 r;
    if (*flag) {
        f32x4 a = ((const f32x4*)in)[(size_t)idx*2];
        f32x4 b = ((const f32x4*)in)[(size_t)idx*2 + 1];
        #pragma unroll
        for (int i = 0; i < 4; i++) { r[i] = (bf16)a[i]; r[i+4] = (bf16)b[i]; }
    } else {
        r = ((const bf16x8*)in)[idx];
    }
    ((bf16x8*)out)[idx] = r;
}

__global__ __launch_bounds__(256) void convert_small(
    const void* s0, const void* s1, const void* s2, const void* s3,
    const void* s4, const void* s5, const void* s6, const void* s7,
    const void* s8, bf16* __restrict__ dst, const int* __restrict__ flag)
{
    const void* srcs[9] = {s0,s1,s2,s3,s4,s5,s6,s7,s8};
    const int sizes[9]  = {512,512,512,512,8192,512,512,512,64};
    const int offs[9]   = {SM_BQ,SM_BK,SM_BV,SM_BO,SM_SRW,SM_SRB,SM_LNG,SM_LNB,SM_TW};
    const float scl[9]  = {0.125f,1.f,1.f,1.f,1.f,1.f,1.f,1.f,1.f};  // bq carries 1/sqrt(dk)
    int b = blockIdx.x;
    const void* s = srcs[b];
    int n = sizes[b], o = offs[b];
    float sc = scl[b];
    bool f32 = (*flag != 0);
    for (int i = threadIdx.x; i < n; i += 256) {
        float v = f32 ? ((const float*)s)[i] : (float)((const bf16*)s)[i];
        dst[o + i] = (bf16)(v * sc);
    }
}

// ---------------- weight transpose (512x512), dtype-aware load ----------------
__global__ __launch_bounds__(256) void transpose512(
    const void* s0, const void* s1, const void* s2, const void* s3,
    bf16* __restrict__ d0, bf16* __restrict__ d1,
    bf16* __restrict__ d2, bf16* __restrict__ d3,
    const int* __restrict__ flag)
{
    __shared__ bf16 tile[32][33];
    bool f32 = (*flag != 0);
    int wsel = blockIdx.z;
    const void* src = wsel == 0 ? s0 : wsel == 1 ? s1 : wsel == 2 ? s2 : s3;
    bf16*       dst = wsel == 0 ? d0 : wsel == 1 ? d1 : wsel == 2 ? d2 : d3;
    float scl = (wsel == 0) ? 0.125f : 1.0f;    // Wq carries 1/sqrt(dk)
    int c0 = blockIdx.x * 32, n0 = blockIdx.y * 32;
    int tx = threadIdx.x, ty = threadIdx.y;   // (32,8)
    #pragma unroll
    for (int i = 0; i < 4; i++) {
        size_t idx = (size_t)(c0 + ty + i*8) * 512 + n0 + tx;
        float v = f32 ? ((const float*)src)[idx] : (float)((const bf16*)src)[idx];
        tile[ty + i*8][tx] = (bf16)(v * scl);
    }
    __syncthreads();
    #pragma unroll
    for (int i = 0; i < 4; i++)
        dst[(size_t)(n0 + ty + i*8) * 512 + c0 + tx] = tile[tx][ty + i*8];
}

// ---------------- depthwise 4x4/s3 conv + LayerNorm ----------------
__global__ __launch_bounds__(256) void sr_ln(
    const bf16* __restrict__ q, const bf16* __restrict__ sm, bf16* __restrict__ x)
{
    const bf16* srw  = sm + SM_SRW;
    const bf16* srb  = sm + SM_SRB;
    const bf16* g    = sm + SM_LNG;
    const bf16* beta = sm + SM_LNB;
    int bo = blockIdx.x;               // b*256 + ok
    int b  = bo >> 8, ok = bo & 255;
    int oh = ok >> 4, ow = ok & 15;
    int t  = threadIdx.x;

    float v[2];
    #pragma unroll
    for (int h = 0; h < 2; h++) {
        int ch = t + h*256;
        float acc = 0.f;
        #pragma unroll
        for (int kh = 0; kh < 4; kh++) {
            int ih = oh*3 - 1 + kh;
            if (ih < 0) continue;
            #pragma unroll
            for (int kw = 0; kw < 4; kw++) {
                int iw = ow*3 - 1 + kw;
                if (iw < 0) continue;
                acc += (float)q[((size_t)b*NQ + ih*48 + iw)*DD + ch]
                     * (float)srw[ch*16 + kh*4 + kw];
            }
        }
        v[h] = acc + (float)srb[ch];
    }
    float s = v[0] + v[1], s2 = v[0]*v[0] + v[1]*v[1];
    #pragma unroll
    for (int m = 1; m < 64; m <<= 1) { s += __shfl_xor(s, m); s2 += __shfl_xor(s2, m); }
    __shared__ float ps[4], ps2[4];
    if ((t & 63) == 0) { ps[t >> 6] = s; ps2[t >> 6] = s2; }
    __syncthreads();
    s  = ps[0] + ps[1] + ps[2] + ps[3];
    s2 = ps2[0] + ps2[1] + ps2[2] + ps2[3];
    float mu  = s * (1.f/512.f);
    float var = s2 * (1.f/512.f) - mu*mu;
    float inv = rsqrtf(var + 1e-5f);
    #pragma unroll
    for (int h = 0; h < 2; h++) {
        int ch = t + h*256;
        float y = (v[h] - mu) * inv * (float)g[ch] + (float)beta[ch];
        x[(size_t)bo * DD + ch] = (bf16)y;
    }
}

// ---------------- generic BT-GEMM: C(M,512) = A(M,512) @ Bt(512,512)^T + bias ----------
// MODE 0: bf16 row-major store.
// MODE 1: V^T scatter store (b,h,dv,kk).
// MODE 2: output GEMM: per-batch Bt block (pre-scaled WoT), dtype-branch store.
template <int MODE>
__global__ __launch_bounds__(256) void gemm_bt(
    const bf16* __restrict__ A, const bf16* __restrict__ Bt,
    const bf16* __restrict__ bias, bf16* __restrict__ C,
    const int* __restrict__ of32)
{
    constexpr int K = 512;
    __shared__ bf16 Al[128 * 64];
    __shared__ bf16 Bl[128 * 64];
    const int m0 = blockIdx.x * 128, n0 = blockIdx.y * 128;
    const int t = threadIdx.x;
    const int lane = t & 63, w = t >> 6;
    const int wr = w >> 1, wc = w & 1;
    const int gg = lane >> 4, li = lane & 15;
    const int fsw = (li & 7) << 4;
    bool f32o = false;
    if (MODE == 2) f32o = (*of32 != 0);

    const bf16* Btb = Bt;
    if (MODE == 2) Btb = Bt + (size_t)(m0 / 2304) * (512 * 512);   // per-batch Wo'

    f32x4 acc[4][4] = {};

    for (int k0 = 0; k0 < K; k0 += 64) {
        #pragma unroll
        for (int p = 0; p < 4; p++) {
            int off = p*4096 + t*16;
            int row = off >> 7;
            int col = ((((off >> 4) & 7) ^ (row & 7)) << 3);
            gload_lds16(A + (size_t)(m0 + row)*K + k0 + col, (char*)Al + off);
        }
        #pragma unroll
        for (int p = 0; p < 4; p++) {
            int off = p*4096 + t*16;
            int row = off >> 7;
            int col = ((((off >> 4) & 7) ^ (row & 7)) << 3);
            gload_lds16(Btb + (size_t)(n0 + row)*K + k0 + col, (char*)Bl + off);
        }
        __syncthreads();
        #pragma unroll
        for (int kk = 0; kk < 2; kk++) {
            bf16x8 af[4], bfr[4];
            #pragma unroll
            for (int i = 0; i < 4; i++) {
                af[i]  = *(const bf16x8*)((char*)Al + (wr*64 + i*16 + li)*128 + ((kk*64 + gg*16) ^ fsw));
                bfr[i] = *(const bf16x8*)((char*)Bl + (wc*64 + i*16 + li)*128 + ((kk*64 + gg*16) ^ fsw));
            }
            __builtin_amdgcn_s_setprio(1);
            #pragma unroll
            for (int i = 0; i < 4; i++)
                #pragma unroll
                for (int j = 0; j < 4; j++)
                    acc[i][j] = __builtin_amdgcn_mfma_f32_16x16x32_bf16(af[i], bfr[j], acc[i][j], 0, 0, 0);
            __builtin_amdgcn_s_setprio(0);
        }
        __syncthreads();
    }

    #pragma unroll
    for (int i = 0; i < 4; i++) {
        #pragma unroll
        for (int j = 0; j < 4; j++) {
            int rbase = m0 + wr*64 + i*16 + gg*4;
            int c     = n0 + wc*64 + j*16 + li;
            float bv = (float)bias[c];
            #pragma unroll
            for (int jj = 0; jj < 4; jj++) {
                float val = acc[i][j][jj] + bv;
                int r = rbase + jj;
                if (MODE == 1) {
                    int bb = r >> 8, kk2 = r & 255;
                    int hh = c >> 6, dv = c & 63;
                    C[(((size_t)(bb*8 + hh))*64 + dv)*256 + kk2] = (bf16)val;
                } else if (MODE == 2) {
                    if (f32o) ((float*)C)[(size_t)r * 512 + c] = val;
                    else      C[(size_t)r * 512 + c] = (bf16)val;
                } else {
                    C[(size_t)r * 512 + c] = (bf16)val;
                }
            }
        }
    }
}

// ---------------- per-batch scaled Wo^T ----------------
__global__ __launch_bounds__(256) void scale_wot(const bf16* __restrict__ WoT,
                                                 const float* __restrict__ ssq,
                                                 bf16* __restrict__ out)
{
    int idx = blockIdx.x * 256 + threadIdx.x;   // 16*512*64 chunks of 8
    int c8 = idx & 63;
    int c  = (idx >> 6) & 511;
    int b  = idx >> 15;
    int h  = c8 >> 3;
    float va = ssq[b*8 + h] * (1.0f / ((float)NQ * (float)NKV));
    float s  = rsqrtf(va + 1e-5f);
    bf16x8 v = *(const bf16x8*)(WoT + ((size_t)c << 9) + c8*8);
    bf16x8 r;
    #pragma unroll
    for (int i = 0; i < 8; i++) r[i] = (bf16)((float)v[i] * s);
    *(bf16x8*)(out + ((size_t)idx << 3)) = r;
}

// ---------------- fused attention: per-head S + in-register mix ----------------
// grid (144, 16) = (q-tile of 16 rows, batch). 512 threads = 8 waves.
// Wave w owns k-band [w*32, w*32+32) during QK/mix, and output head o=w in PV.
__global__ __launch_bounds__(512, 2) void attn_fused(
    const bf16* __restrict__ Qf, const bf16* __restrict__ Kt,
    const bf16* __restrict__ VT, const bf16* __restrict__ sm,
    bf16* __restrict__ U, float* __restrict__ ssq_g)
{
    __shared__ bf16 Ql[16 * 512];        // 16 KB, rows 1024 B, XOR-swizzled
    __shared__ bf16 Kl[2][256 * 64];     // 64 KB, rows 128 B, XOR-swizzled
    __shared__ bf16 Pl[8 * 16 * 256];    // 64 KB, dev per o, rows 512 B, swizzled
    __shared__ float srow[8 * 16 * 8];   // [o][q][w] rowsum partials
    __shared__ float rpar[8][8];         // [w][o] ssq partials

    const int t = threadIdx.x;
    const int lane = t & 63, w = t >> 6;
    const int gg = lane >> 4, li = lane & 15;
    const int qt = blockIdx.x, b = blockIdx.y;
    const int q0 = qt * 16;

    // ---- stage Q (16x512) and K_0 ----
    #pragma unroll
    for (int p = 0; p < 2; p++) {
        int off = p*8192 + t*16;
        int q = off >> 10, slot = (off >> 4) & 63;
        gload_lds16(Qf + ((size_t)(b*NQ + q0 + q))*DD + ((slot ^ (q & 7)) << 3),
                    (char*)Ql + off);
    }
    #pragma unroll
    for (int p = 0; p < 4; p++) {
        int off = p*8192 + t*16;
        int kr = off >> 7, slot = (off >> 4) & 7;
        gload_lds16(Kt + ((size_t)(b*NKV + kr))*DD + ((slot ^ (kr & 7)) << 3),
                    (char*)Kl[0] + off);
    }

    f32x4 acc[8][2] = {};

    #pragma unroll
    for (int i = 0; i < 8; i++) {
        __syncthreads();
        if (i < 7) {
            #pragma unroll
            for (int p = 0; p < 4; p++) {
                int off = p*8192 + t*16;
                int kr = off >> 7, slot = (off >> 4) & 7;
                gload_lds16(Kt + ((size_t)(b*NKV + kr))*DD + (i+1)*64 + ((slot ^ (kr & 7)) << 3),
                            (char*)Kl[(i+1) & 1] + off);
            }
        }
        #pragma unroll
        for (int kk = 0; kk < 2; kk++) {
            bf16x8 af = *(const bf16x8*)((char*)Ql + li*1024
                          + ((i*128 + kk*64 + gg*16) ^ ((li & 7) << 4)));
            #pragma unroll
            for (int nt = 0; nt < 2; nt++) {
                int kr = w*32 + nt*16 + li;
                bf16x8 bfr = *(const bf16x8*)((char*)Kl[i & 1] + kr*128
                               + ((kk*64 + gg*16) ^ ((kr & 7) << 4)));
                acc[i][nt] = __builtin_amdgcn_mfma_f32_16x16x32_bf16(af, bfr, acc[i][nt], 0, 0, 0);
            }
        }
    }

    // ---- mix (tw) + exp + per-o row-sum partials ----
    // lane's acc element (i, nt, r) is S_i at (q = gg*4+r, k = w*32 + nt*16 + li)
    f32x4 e[8][2];
    #pragma unroll
    for (int o = 0; o < 8; o++) {
        #pragma unroll
        for (int nt = 0; nt < 2; nt++) {
            #pragma unroll
            for (int r = 0; r < 4; r++) {
                float a = 0.f;
                #pragma unroll
                for (int i = 0; i < 8; i++)
                    a += (float)sm[SM_TW + o*8 + i] * acc[i][nt][r];
                a = fminf(fmaxf(a, -30.f), 30.f);
                e[o][nt][r] = __expf(a);
            }
        }
        #pragma unroll
        for (int r = 0; r < 4; r++) {
            float s = e[o][0][r] + e[o][1][r];
            s += __shfl_xor(s, 1); s += __shfl_xor(s, 2);
            s += __shfl_xor(s, 4); s += __shfl_xor(s, 8);
            if (li == 0) srow[(o*16 + gg*4 + r)*8 + w] = s;
        }
    }
    __syncthreads();

    // ---- normalize, dev, ssq, write Pl ----
    float lssq[8];
    #pragma unroll
    for (int o = 0; o < 8; o++) lssq[o] = 0.f;
    #pragma unroll
    for (int o = 0; o < 8; o++) {
        #pragma unroll
        for (int r = 0; r < 4; r++) {
            int q = gg*4 + r;
            f32x4 s0 = *(const f32x4*)&srow[(o*16 + q)*8];
            f32x4 s1 = *(const f32x4*)&srow[(o*16 + q)*8 + 4];
            float inv = 1.0f / (s0[0]+s0[1]+s0[2]+s0[3]+s1[0]+s1[1]+s1[2]+s1[3]);
            #pragma unroll
            for (int nt = 0; nt < 2; nt++) {
                float dev = e[o][nt][r] * inv - (1.0f/256.0f);
                lssq[o] += dev * dev;
                int k = w*32 + nt*16 + li;
                *(bf16*)((char*)Pl + o*8192 + q*512 + ((k*2) ^ ((q & 7) << 4))) = (bf16)dev;
            }
        }
    }
    #pragma unroll
    for (int o = 0; o < 8; o++) {
        float s = lssq[o];
        #pragma unroll
        for (int m = 1; m < 64; m <<= 1) s += __shfl_xor(s, m);
        if (lane == 0) rpar[w][o] = s;
    }
    __syncthreads();

    // ---- PV: wave w = output head o ----
    const int o = w;
    f32x4 u[4] = {};
    const bf16* Vb = VT + ((size_t)((b*8 + o) * 64)) * 256;
    #pragma unroll
    for (int s = 0; s < 8; s++) {
        bf16x8 pa = *(const bf16x8*)((char*)Pl + o*8192 + li*512
                      + (((s*32 + gg*8)*2) ^ ((li & 7) << 4)));
        __builtin_amdgcn_s_setprio(1);
        #pragma unroll
        for (int dvt = 0; dvt < 4; dvt++) {
            bf16x8 vb = *(const bf16x8*)(Vb + (size_t)(dvt*16 + li)*256 + s*32 + gg*8);
            u[dvt] = __builtin_amdgcn_mfma_f32_16x16x32_bf16(pa, vb, u[dvt], 0, 0, 0);
        }
        __builtin_amdgcn_s_setprio(0);
    }
    bf16* Ub = U + ((size_t)(b*NQ + q0)) * DD + o*64;
    #pragma unroll
    for (int dvt = 0; dvt < 4; dvt++)
        #pragma unroll
        for (int jj = 0; jj < 4; jj++)
            Ub[(size_t)(gg*4 + jj) * DD + dvt*16 + li] = (bf16)u[dvt][jj];

    if (t < 8) {
        float tot = 0.f;
        #pragma unroll
        for (int i = 0; i < 8; i++) tot += rpar[i][t];
        atomicAdd(&ssq_g[b*8 + t], tot);
    }
}

// ======================================================================
extern "C" void kernel_launch(void* const* d_in, const int* in_sizes, int n_in,
                              void* d_out, int out_size, void* d_ws, size_t ws_size,
                              hipStream_t stream)
{
    const void* queries = d_in[0];
    const void* Wq = d_in[1];  const void* bq = d_in[2];
    const void* Wk = d_in[3];  const void* bk = d_in[4];
    const void* Wv = d_in[5];  const void* bv = d_in[6];
    const void* Wo = d_in[7];  const void* bo = d_in[8];
    const void* srw = d_in[9]; const void* srb = d_in[10];
    const void* lng = d_in[11]; const void* lnb = d_in[12];
    const void* tw  = d_in[13];
    // d_in[14] = tb: cancels in softmax; unused.

    char* ws = (char*)d_ws;
    bf16* WqT = (bf16*)(ws + OFF_WQT);
    bf16* WkT = (bf16*)(ws + OFF_WKT);
    bf16* WvT = (bf16*)(ws + OFF_WVT);
    bf16* WoT = (bf16*)(ws + OFF_WOT);
    bf16* xb  = (bf16*)(ws + OFF_X);
    bf16* Kt  = (bf16*)(ws + OFF_KT);
    bf16* VTb = (bf16*)(ws + OFF_VT);
    bf16* Qf  = (bf16*)(ws + OFF_QF);
    bf16* Ub  = (bf16*)(ws + OFF_U);
    float* ss = (float*)(ws + OFF_SS);
    bf16* sm  = (bf16*)(ws + OFF_SM);
    int* flag = (int*)(ws + OFF_FLG);
    bf16* WoTp = (bf16*)(ws + OFF_WOTP);   // aliases xb+Kt, dead by scale_wot time
    bf16* Qc  = Ub;                         // canonical queries in U region (dead until attn)

    detect_dtype<<<dim3(1), dim3(64), 0, stream>>>((const uint32_t*)queries, flag);
    hipMemsetAsync(ss, 0, 128 * sizeof(float), stream);

    convert_q<<<dim3(9216), dim3(256), 0, stream>>>(queries, Qc, flag);
    convert_small<<<dim3(9), dim3(256), 0, stream>>>(bq, bk, bv, bo, srw, srb, lng, lnb, tw, sm, flag);
    transpose512<<<dim3(16, 16, 4), dim3(32, 8), 0, stream>>>(Wq, Wk, Wv, Wo, WqT, WkT, WvT, WoT, flag);

    sr_ln<<<dim3(NB * NKV), dim3(256), 0, stream>>>(Qc, sm, xb);
    gemm_bt<0><<<dim3(32, 4), dim3(256), 0, stream>>>(xb, WkT, sm + SM_BK, Kt, nullptr);
    gemm_bt<1><<<dim3(32, 4), dim3(256), 0, stream>>>(xb, WvT, sm + SM_BV, VTb, nullptr);
    gemm_bt<0><<<dim3(288, 4), dim3(256), 0, stream>>>(Qc, WqT, sm + SM_BQ, Qf, nullptr);

    attn_fused<<<dim3(144, 16), dim3(512), 0, stream>>>(Qf, Kt, VTb, sm, Ub, ss);

    scale_wot<<<dim3(2048), dim3(256), 0, stream>>>(WoT, ss, WoTp);
    gemm_bt<2><<<dim3(288, 4), dim3(256), 0, stream>>>(Ub, WoTp, sm + SM_BO, (bf16*)d_out, flag);
}

// Round 7
// 337.849 us; speedup vs baseline: 1.1957x; 1.1957x over previous
//
#include <hip/hip_runtime.h>
#include <hip/hip_bf16.h>
#include <stdint.h>

// ======================================================================
// EMSA fused pipeline. Device dtype (bf16 vs f32) detected at runtime.
// Algebra:
//  * S_i = Q_i K_i^T /8 once per input head (9.7 GF); head-mix tw applied
//    in a streaming VALU kernel; PV is a clean batched GEMM.
//  * softmax row-sums are 1  =>  instance-norm mean = 1/256 exactly
//  * Dev = P - 1/256; var = mean(Dev^2); out = (Dev@V)*rsqrt(va+eps)
//  * tb cancels in softmax; 1/sqrt(dk) folded into WqT/bq;
//    instance-norm scale folded into per-batch pre-scaled Wo^T.
// R7: fixed R6's zero-output bug — __builtin_amdgcn_readfirstlane(float)
//     implicitly converted 0.02f -> (int)0 -> tw==0 -> Dev==0 -> out==0.
//     tw now loaded with plain (uniform-address) loads.
// ======================================================================

typedef __bf16 bf16;
typedef __bf16 bf16x4 __attribute__((ext_vector_type(4)));
typedef __bf16 bf16x8 __attribute__((ext_vector_type(8)));
typedef float  f32x4  __attribute__((ext_vector_type(4)));

#define LDS_AS  __attribute__((address_space(3)))
#define GLOB_AS __attribute__((address_space(1)))

__device__ __forceinline__ void gload_lds16(const bf16* g, void* l) {
    __builtin_amdgcn_global_load_lds((const GLOB_AS void*)g, (LDS_AS void*)l, 16, 0, 0);
}

// ---------------- constants ----------------
#define NB   16
#define NQ   2304
#define DD   512
#define NKV  256

// workspace layout (bytes)
constexpr size_t OFF_WQT = 0;
constexpr size_t OFF_WKT = 512*512*2;
constexpr size_t OFF_WVT = 2*512*512*2;
constexpr size_t OFF_WOT = 3*512*512*2;
constexpr size_t OFF_X   = 4*512*512*2;                  //  2,097,152  (4 MB region)
constexpr size_t OFF_KT  = OFF_X  + 4194304;             //  6,291,456  (4 MB)
constexpr size_t OFF_VT  = OFF_KT + 4194304;             // 10,485,760  (4 MB)
constexpr size_t OFF_SS  = OFF_VT + 4194304;             // 14,680,064  (128 f32)
constexpr size_t OFF_SM  = OFF_SS + 512;
constexpr size_t OFF_TWF = OFF_SM + 24064;
constexpr size_t OFF_FLG = OFF_TWF + 256;
constexpr size_t OFF_QF  = OFF_FLG + 256;                // 14,705,152  (37.75 MB)
constexpr size_t OFF_U   = OFF_QF + (size_t)NB*NQ*DD*2;  // 52,453,888  (37.75 MB)
constexpr size_t OFF_S   = OFF_U  + (size_t)NB*NQ*DD*2;  // 90,202,624  (CB*9.44 MB)
constexpr size_t SPLANE  = (size_t)NQ*NKV*2;             // one (q,k) plane = 1,179,648 B
constexpr size_t OFF_WOTP = OFF_X;  // 16*512*512*2 = 8,388,608 B = exactly X+KT (dead by then)

// small-region element offsets
#define SM_BQ  0
#define SM_BK  512
#define SM_BV  1024
#define SM_BO  1536
#define SM_SRW 2048
#define SM_SRB 10240
#define SM_LNG 10752
#define SM_LNB 11264
#define SM_TW  11776

// ---------------- dtype detection ----------------
__global__ __launch_bounds__(64) void detect_dtype(const uint32_t* __restrict__ q,
                                                   int* __restrict__ flag)
{
    int t = threadIdx.x;
    int cnt = 0;
    #pragma unroll
    for (int i = 0; i < 8; i++) {
        uint32_t w = q[t*8 + i];
        int e = (w >> 7) & 0xFF;
        cnt += (e >= 100 && e <= 150) ? 1 : 0;
    }
    #pragma unroll
    for (int m = 1; m < 64; m <<= 1) cnt += __shfl_xor(cnt, m);
    if (t == 0) *flag = (cnt >= 384) ? 0 : 1;   // 0=bf16, 1=f32
}

// ---------------- input conversion (work only for f32 input) ----------------
__global__ __launch_bounds__(256) void convert_q(const void* __restrict__ in,
                                                 bf16* __restrict__ out,
                                                 const int* __restrict__ flag)
{
    if (*flag == 0) return;    // bf16 input: consumers read the raw buffer
    int idx = blockIdx.x * 256 + threadIdx.x;
    f32x4 a = ((const f32x4*)in)[(size_t)idx*2];
    f32x4 b = ((const f32x4*)in)[(size_t)idx*2 + 1];
    bf16x8 r;
    #pragma unroll
    for (int i = 0; i < 4; i++) { r[i] = (bf16)a[i]; r[i+4] = (bf16)b[i]; }
    ((bf16x8*)out)[idx] = r;
}

__global__ __launch_bounds__(256) void convert_small(
    const void* s0, const void* s1, const void* s2, const void* s3,
    const void* s4, const void* s5, const void* s6, const void* s7,
    const void* s8, bf16* __restrict__ dst, float* __restrict__ twf,
    const int* __restrict__ flag)
{
    const void* srcs[9] = {s0,s1,s2,s3,s4,s5,s6,s7,s8};
    const int sizes[9]  = {512,512,512,512,8192,512,512,512,64};
    const int offs[9]   = {SM_BQ,SM_BK,SM_BV,SM_BO,SM_SRW,SM_SRB,SM_LNG,SM_LNB,SM_TW};
    const float scl[9]  = {0.125f,1.f,1.f,1.f,1.f,1.f,1.f,1.f,1.f};  // bq carries 1/sqrt(dk)
    int b = blockIdx.x;
    const void* s = srcs[b];
    int n = sizes[b], o = offs[b];
    float sc = scl[b];
    bool f32 = (*flag != 0);
    for (int i = threadIdx.x; i < n; i += 256) {
        float v = f32 ? ((const float*)s)[i] : (float)((const bf16*)s)[i];
        dst[o + i] = (bf16)(v * sc);
        if (b == 8) twf[i] = v;
    }
}

// ---------------- weight transpose (512x512), dtype-aware load ----------------
__global__ __launch_bounds__(256) void transpose512(
    const void* s0, const void* s1, const void* s2, const void* s3,
    bf16* __restrict__ d0, bf16* __restrict__ d1,
    bf16* __restrict__ d2, bf16* __restrict__ d3,
    const int* __restrict__ flag)
{
    __shared__ bf16 tile[32][33];
    bool f32 = (*flag != 0);
    int wsel = blockIdx.z;
    const void* src = wsel == 0 ? s0 : wsel == 1 ? s1 : wsel == 2 ? s2 : s3;
    bf16*       dst = wsel == 0 ? d0 : wsel == 1 ? d1 : wsel == 2 ? d2 : d3;
    float scl = (wsel == 0) ? 0.125f : 1.0f;    // Wq carries 1/sqrt(dk)
    int c0 = blockIdx.x * 32, n0 = blockIdx.y * 32;
    int tx = threadIdx.x, ty = threadIdx.y;   // (32,8)
    #pragma unroll
    for (int i = 0; i < 4; i++) {
        size_t idx = (size_t)(c0 + ty + i*8) * 512 + n0 + tx;
        float v = f32 ? ((const float*)src)[idx] : (float)((const bf16*)src)[idx];
        tile[ty + i*8][tx] = (bf16)(v * scl);
    }
    __syncthreads();
    #pragma unroll
    for (int i = 0; i < 4; i++)
        dst[(size_t)(n0 + ty + i*8) * 512 + c0 + tx] = tile[tx][ty + i*8];
}

// ---------------- depthwise 4x4/s3 conv + LayerNorm ----------------
__global__ __launch_bounds__(256) void sr_ln(
    const void* __restrict__ qraw, const bf16* __restrict__ qc,
    const bf16* __restrict__ sm, bf16* __restrict__ x,
    const int* __restrict__ flag)
{
    const bf16* q = (*flag) ? qc : (const bf16*)qraw;
    const bf16* srw  = sm + SM_SRW;
    const bf16* srb  = sm + SM_SRB;
    const bf16* g    = sm + SM_LNG;
    const bf16* beta = sm + SM_LNB;
    int bo = blockIdx.x;               // b*256 + ok
    int b  = bo >> 8, ok = bo & 255;
    int oh = ok >> 4, ow = ok & 15;
    int t  = threadIdx.x;

    float v[2];
    #pragma unroll
    for (int h = 0; h < 2; h++) {
        int ch = t + h*256;
        float acc = 0.f;
        #pragma unroll
        for (int kh = 0; kh < 4; kh++) {
            int ih = oh*3 - 1 + kh;
            if (ih < 0) continue;
            #pragma unroll
            for (int kw = 0; kw < 4; kw++) {
                int iw = ow*3 - 1 + kw;
                if (iw < 0) continue;
                acc += (float)q[((size_t)b*NQ + ih*48 + iw)*DD + ch]
                     * (float)srw[ch*16 + kh*4 + kw];
            }
        }
        v[h] = acc + (float)srb[ch];
    }
    float s = v[0] + v[1], s2 = v[0]*v[0] + v[1]*v[1];
    #pragma unroll
    for (int m = 1; m < 64; m <<= 1) { s += __shfl_xor(s, m); s2 += __shfl_xor(s2, m); }
    __shared__ float ps[4], ps2[4];
    if ((t & 63) == 0) { ps[t >> 6] = s; ps2[t >> 6] = s2; }
    __syncthreads();
    s  = ps[0] + ps[1] + ps[2] + ps[3];
    s2 = ps2[0] + ps2[1] + ps2[2] + ps2[3];
    float mu  = s * (1.f/512.f);
    float var = s2 * (1.f/512.f) - mu*mu;
    float inv = rsqrtf(var + 1e-5f);
    #pragma unroll
    for (int h = 0; h < 2; h++) {
        int ch = t + h*256;
        float y = (v[h] - mu) * inv * (float)g[ch] + (float)beta[ch];
        x[(size_t)bo * DD + ch] = (bf16)y;
    }
}

// ---------------- generic BT-GEMM: C(M,512) = A(M,512) @ Bt(512,512)^T + bias ----------
// MODE 0: bf16 row-major store.
// MODE 1: V^T scatter store (b,h,dv,kk).
// MODE 2: output GEMM: per-batch Bt block (pre-scaled WoT), dtype-branch store.
// MODE 4: A chosen by flag (raw vs converted queries).
template <int MODE>
__global__ __launch_bounds__(256) void gemm_bt(
    const bf16* __restrict__ A, const bf16* __restrict__ Bt,
    const bf16* __restrict__ bias, bf16* __restrict__ C,
    const int* __restrict__ of32, const bf16* __restrict__ A2)
{
    constexpr int K = 512;
    __shared__ bf16 Al[128 * 64];
    __shared__ bf16 Bl[128 * 64];
    const int m0 = blockIdx.x * 128, n0 = blockIdx.y * 128;
    const int t = threadIdx.x;
    const int lane = t & 63, w = t >> 6;
    const int wr = w >> 1, wc = w & 1;
    const int gg = lane >> 4, li = lane & 15;
    const int fsw = (li & 7) << 4;
    bool f32o = false;
    if (MODE == 2) f32o = (*of32 != 0);

    const bf16* Ab = A;
    if (MODE == 4) Ab = (*of32) ? A2 : A;
    const bf16* Btb = Bt;
    if (MODE == 2) Btb = Bt + (size_t)(m0 / 2304) * (512 * 512);   // per-batch Wo'

    f32x4 acc[4][4] = {};

    for (int k0 = 0; k0 < K; k0 += 64) {
        #pragma unroll
        for (int p = 0; p < 4; p++) {
            int off = p*4096 + t*16;
            int row = off >> 7;
            int col = ((((off >> 4) & 7) ^ (row & 7)) << 3);
            gload_lds16(Ab + (size_t)(m0 + row)*K + k0 + col, (char*)Al + off);
        }
        #pragma unroll
        for (int p = 0; p < 4; p++) {
            int off = p*4096 + t*16;
            int row = off >> 7;
            int col = ((((off >> 4) & 7) ^ (row & 7)) << 3);
            gload_lds16(Btb + (size_t)(n0 + row)*K + k0 + col, (char*)Bl + off);
        }
        __syncthreads();
        #pragma unroll
        for (int kk = 0; kk < 2; kk++) {
            bf16x8 af[4], bfr[4];
            #pragma unroll
            for (int i = 0; i < 4; i++) {
                af[i]  = *(const bf16x8*)((char*)Al + (wr*64 + i*16 + li)*128 + ((kk*64 + gg*16) ^ fsw));
                bfr[i] = *(const bf16x8*)((char*)Bl + (wc*64 + i*16 + li)*128 + ((kk*64 + gg*16) ^ fsw));
            }
            __builtin_amdgcn_s_setprio(1);
            #pragma unroll
            for (int i = 0; i < 4; i++)
                #pragma unroll
                for (int j = 0; j < 4; j++)
                    acc[i][j] = __builtin_amdgcn_mfma_f32_16x16x32_bf16(af[i], bfr[j], acc[i][j], 0, 0, 0);
            __builtin_amdgcn_s_setprio(0);
        }
        __syncthreads();
    }

    #pragma unroll
    for (int i = 0; i < 4; i++) {
        #pragma unroll
        for (int j = 0; j < 4; j++) {
            int rbase = m0 + wr*64 + i*16 + gg*4;
            int c     = n0 + wc*64 + j*16 + li;
            float bv = (float)bias[c];
            #pragma unroll
            for (int jj = 0; jj < 4; jj++) {
                float val = acc[i][j][jj] + bv;
                int r = rbase + jj;
                if (MODE == 1) {
                    int bb = r >> 8, kk2 = r & 255;
                    int hh = c >> 6, dv = c & 63;
                    C[(((size_t)(bb*8 + hh))*64 + dv)*256 + kk2] = (bf16)val;
                } else if (MODE == 2) {
                    if (f32o) ((float*)C)[(size_t)r * 512 + c] = val;
                    else      C[(size_t)r * 512 + c] = (bf16)val;
                } else {
                    C[(size_t)r * 512 + c] = (bf16)val;
                }
            }
        }
    }
}

// ---------------- S-GEMM: S[plane] = Q_i @ K_i^T  (M=2304,N=256,K=64) ----------------
// grid (18, 2, CB*8); plane index is LOCAL to the chunk buffer.
__global__ __launch_bounds__(256) void gemm_s(
    const bf16* __restrict__ Qf, const bf16* __restrict__ Kt, bf16* __restrict__ S,
    int b0)
{
    __shared__ bf16 Al[128 * 64];
    __shared__ bf16 Bl[128 * 64];
    const int m0 = blockIdx.x * 128, n0 = blockIdx.y * 128;
    const int bo = blockIdx.z;                 // local plane
    const int b = b0 + (bo >> 3), ih = bo & 7; // global batch, input head
    const int t = threadIdx.x;
    const int lane = t & 63, w = t >> 6;
    const int wr = w >> 1, wc = w & 1;
    const int gg = lane >> 4, li = lane & 15;
    const int fsw = (li & 7) << 4;

    #pragma unroll
    for (int p = 0; p < 4; p++) {
        int off = p*4096 + t*16;
        int row = off >> 7;
        int col = ((((off >> 4) & 7) ^ (row & 7)) << 3);
        gload_lds16(Qf + ((size_t)(b*NQ + m0 + row))*DD + ih*64 + col, (char*)Al + off);
    }
    #pragma unroll
    for (int p = 0; p < 4; p++) {
        int off = p*4096 + t*16;
        int row = off >> 7;
        int col = ((((off >> 4) & 7) ^ (row & 7)) << 3);
        gload_lds16(Kt + ((size_t)(b*NKV + n0 + row))*DD + ih*64 + col, (char*)Bl + off);
    }
    __syncthreads();

    f32x4 acc[4][4] = {};
    #pragma unroll
    for (int kk = 0; kk < 2; kk++) {
        bf16x8 af[4], bfr[4];
        #pragma unroll
        for (int i = 0; i < 4; i++) {
            af[i]  = *(const bf16x8*)((char*)Al + (wr*64 + i*16 + li)*128 + ((kk*64 + gg*16) ^ fsw));
            bfr[i] = *(const bf16x8*)((char*)Bl + (wc*64 + i*16 + li)*128 + ((kk*64 + gg*16) ^ fsw));
        }
        __builtin_amdgcn_s_setprio(1);
        #pragma unroll
        for (int i = 0; i < 4; i++)
            #pragma unroll
            for (int j = 0; j < 4; j++)
                acc[i][j] = __builtin_amdgcn_mfma_f32_16x16x32_bf16(af[i], bfr[j], acc[i][j], 0, 0, 0);
        __builtin_amdgcn_s_setprio(0);
    }

    bf16* Sb = S + (size_t)bo * NQ * NKV;
    #pragma unroll
    for (int i = 0; i < 4; i++) {
        #pragma unroll
        for (int j = 0; j < 4; j++) {
            int rbase = m0 + wr*64 + i*16 + gg*4;
            int c     = n0 + wc*64 + j*16 + li;
            #pragma unroll
            for (int jj = 0; jj < 4; jj++)
                Sb[(size_t)(rbase + jj) * NKV + c] = (bf16)acc[i][j][jj];
        }
    }
}

// ---------------- mix + softmax + dev + ssq (streaming, IN-PLACE on S) ----------------
// grid (72, CB); 256 thr = 4 waves; wave handles 8 q-rows; lane covers k=lane*4..+4.
__global__ __launch_bounds__(256) void mix_softmax(
    bf16* __restrict__ S, const float* __restrict__ twf,
    float* __restrict__ ssq_g, int b0)
{
    const int t = threadIdx.x;
    const int lane = t & 63, w = t >> 6;
    const int bl = blockIdx.y;            // local batch in chunk
    const int b  = b0 + bl;               // global batch
    const int q0 = blockIdx.x * 32 + w * 8;
    __shared__ float rpar[4][8];

    float tw[8][8];
    #pragma unroll
    for (int o = 0; o < 8; o++)
        #pragma unroll
        for (int i = 0; i < 8; i++)
            tw[o][i] = twf[o*8 + i];     // uniform address -> scalar load

    float ssqL[8] = {};
    for (int qi = 0; qi < 8; qi++) {
        float s[8][4];
        #pragma unroll
        for (int i = 0; i < 8; i++) {
            bf16x4 v = *(const bf16x4*)(S + (((size_t)(bl*8 + i))*NQ + (q0 + qi))*NKV + lane*4);
            #pragma unroll
            for (int r = 0; r < 4; r++) s[i][r] = (float)v[r];
        }
        float e[8][4], inv[8];
        #pragma unroll
        for (int o = 0; o < 8; o++) {
            float sum = 0.f;
            #pragma unroll
            for (int r = 0; r < 4; r++) {
                float a = 0.f;
                #pragma unroll
                for (int i = 0; i < 8; i++) a += tw[o][i] * s[i][r];
                a = fminf(fmaxf(a, -30.f), 30.f);
                e[o][r] = __expf(a);
                sum += e[o][r];
            }
            #pragma unroll
            for (int m = 1; m < 64; m <<= 1) sum += __shfl_xor(sum, m);
            inv[o] = 1.0f / sum;
        }
        #pragma unroll
        for (int o = 0; o < 8; o++) {
            bf16x4 dv;
            #pragma unroll
            for (int r = 0; r < 4; r++) {
                float d = e[o][r] * inv[o] - (1.0f/256.0f);
                ssqL[o] += d * d;
                dv[r] = (bf16)d;
            }
            *(bf16x4*)(S + (((size_t)(bl*8 + o))*NQ + (q0 + qi))*NKV + lane*4) = dv;
        }
    }
    #pragma unroll
    for (int o = 0; o < 8; o++) {
        float s = ssqL[o];
        #pragma unroll
        for (int m = 1; m < 64; m <<= 1) s += __shfl_xor(s, m);
        if (lane == 0) rpar[w][o] = s;
    }
    __syncthreads();
    if (t < 8) {
        float tot = rpar[0][t] + rpar[1][t] + rpar[2][t] + rpar[3][t];
        atomicAdd(&ssq_g[b*8 + t], tot);
    }
}

// ---------------- PV-GEMM: U[b, o-cols] = Dev[plane] @ V[b,o]  (M=2304,N=64,K=256) ----
// grid (18, CB*8)
__global__ __launch_bounds__(256) void gemm_pv(
    const bf16* __restrict__ Dev, const bf16* __restrict__ VT, bf16* __restrict__ U,
    int b0)
{
    __shared__ bf16 Al[128 * 64];
    __shared__ bf16 Bl[64 * 64];
    const int m0 = blockIdx.x * 128;
    const int bo = blockIdx.y;                 // local plane
    const int b = b0 + (bo >> 3), o = bo & 7;  // global batch, out head
    const int t = threadIdx.x;
    const int lane = t & 63, w = t >> 6;
    const int wr = w >> 1, wc = w & 1;
    const int gg = lane >> 4, li = lane & 15;
    const int fsw = (li & 7) << 4;

    const bf16* Ab = Dev + (size_t)bo * NQ * NKV;
    const bf16* Bb = VT + ((size_t)(b*8 + o)) * 64 * NKV;

    f32x4 acc[4][2] = {};

    for (int k0 = 0; k0 < 256; k0 += 64) {
        #pragma unroll
        for (int p = 0; p < 4; p++) {
            int off = p*4096 + t*16;
            int row = off >> 7;
            int col = ((((off >> 4) & 7) ^ (row & 7)) << 3);
            gload_lds16(Ab + (size_t)(m0 + row)*NKV + k0 + col, (char*)Al + off);
        }
        #pragma unroll
        for (int p = 0; p < 2; p++) {
            int off = p*4096 + t*16;
            int row = off >> 7;
            int col = ((((off >> 4) & 7) ^ (row & 7)) << 3);
            gload_lds16(Bb + (size_t)row*NKV + k0 + col, (char*)Bl + off);
        }
        __syncthreads();
        #pragma unroll
        for (int kk = 0; kk < 2; kk++) {
            bf16x8 af[4], bfr[2];
            #pragma unroll
            for (int i = 0; i < 4; i++)
                af[i] = *(const bf16x8*)((char*)Al + (wr*64 + i*16 + li)*128 + ((kk*64 + gg*16) ^ fsw));
            #pragma unroll
            for (int j = 0; j < 2; j++)
                bfr[j] = *(const bf16x8*)((char*)Bl + (wc*32 + j*16 + li)*128 + ((kk*64 + gg*16) ^ fsw));
            __builtin_amdgcn_s_setprio(1);
            #pragma unroll
            for (int i = 0; i < 4; i++)
                #pragma unroll
                for (int j = 0; j < 2; j++)
                    acc[i][j] = __builtin_amdgcn_mfma_f32_16x16x32_bf16(af[i], bfr[j], acc[i][j], 0, 0, 0);
            __builtin_amdgcn_s_setprio(0);
        }
        __syncthreads();
    }

    #pragma unroll
    for (int i = 0; i < 4; i++) {
        #pragma unroll
        for (int j = 0; j < 2; j++) {
            int rbase = m0 + wr*64 + i*16 + gg*4;
            int c = wc*32 + j*16 + li;
            #pragma unroll
            for (int jj = 0; jj < 4; jj++)
                U[((size_t)b*NQ + rbase + jj)*DD + o*64 + c] = (bf16)acc[i][j][jj];
        }
    }
}

// ---------------- per-batch scaled Wo^T ----------------
__global__ __launch_bounds__(256) void scale_wot(const bf16* __restrict__ WoT,
                                                 const float* __restrict__ ssq,
                                                 bf16* __restrict__ out)
{
    int idx = blockIdx.x * 256 + threadIdx.x;   // 16*512*64 chunks of 8
    int c8 = idx & 63;
    int c  = (idx >> 6) & 511;
    int b  = idx >> 15;
    int h  = c8 >> 3;
    float va = ssq[b*8 + h] * (1.0f / ((float)NQ * (float)NKV));
    float s  = rsqrtf(va + 1e-5f);
    bf16x8 v = *(const bf16x8*)(WoT + ((size_t)c << 9) + c8*8);
    bf16x8 r;
    #pragma unroll
    for (int i = 0; i < 8; i++) r[i] = (bf16)((float)v[i] * s);
    *(bf16x8*)(out + ((size_t)idx << 3)) = r;
}

// ======================================================================
extern "C" void kernel_launch(void* const* d_in, const int* in_sizes, int n_in,
                              void* d_out, int out_size, void* d_ws, size_t ws_size,
                              hipStream_t stream)
{
    const void* queries = d_in[0];
    const void* Wq = d_in[1];  const void* bq = d_in[2];
    const void* Wk = d_in[3];  const void* bk = d_in[4];
    const void* Wv = d_in[5];  const void* bv = d_in[6];
    const void* Wo = d_in[7];  const void* bo = d_in[8];
    const void* srw = d_in[9]; const void* srb = d_in[10];
    const void* lng = d_in[11]; const void* lnb = d_in[12];
    const void* tw  = d_in[13];
    // d_in[14] = tb: cancels in softmax; unused.

    char* ws = (char*)d_ws;
    bf16* WqT = (bf16*)(ws + OFF_WQT);
    bf16* WkT = (bf16*)(ws + OFF_WKT);
    bf16* WvT = (bf16*)(ws + OFF_WVT);
    bf16* WoT = (bf16*)(ws + OFF_WOT);
    bf16* xb  = (bf16*)(ws + OFF_X);
    bf16* Kt  = (bf16*)(ws + OFF_KT);
    bf16* VTb = (bf16*)(ws + OFF_VT);
    bf16* Qf  = (bf16*)(ws + OFF_QF);
    bf16* Ub  = (bf16*)(ws + OFF_U);
    float* ss = (float*)(ws + OFF_SS);
    bf16* sm  = (bf16*)(ws + OFF_SM);
    float* twf = (float*)(ws + OFF_TWF);
    int* flag = (int*)(ws + OFF_FLG);
    bf16* WoTp = (bf16*)(ws + OFF_WOTP);   // aliases xb+Kt (both dead by scale_wot)
    bf16* Sb  = (bf16*)(ws + OFF_S);       // S/Dev chunk buffer (in-place mix)
    bf16* Qc  = Ub;                        // converted queries (f32 path); dead before U written

    // chunk size: largest CB whose S buffer fits the workspace
    int CB = 1;
    if      (OFF_S + 16*8*SPLANE <= ws_size) CB = 16;
    else if (OFF_S +  8*8*SPLANE <= ws_size) CB = 8;
    else if (OFF_S +  4*8*SPLANE <= ws_size) CB = 4;
    else if (OFF_S +  2*8*SPLANE <= ws_size) CB = 2;

    detect_dtype<<<dim3(1), dim3(64), 0, stream>>>((const uint32_t*)queries, flag);
    hipMemsetAsync(ss, 0, 128 * sizeof(float), stream);

    convert_q<<<dim3(9216), dim3(256), 0, stream>>>(queries, Qc, flag);
    convert_small<<<dim3(9), dim3(256), 0, stream>>>(bq, bk, bv, bo, srw, srb, lng, lnb, tw, sm, twf, flag);
    transpose512<<<dim3(16, 16, 4), dim3(32, 8), 0, stream>>>(Wq, Wk, Wv, Wo, WqT, WkT, WvT, WoT, flag);

    sr_ln<<<dim3(NB * NKV), dim3(256), 0, stream>>>(queries, Qc, sm, xb, flag);
    gemm_bt<0><<<dim3(32, 4), dim3(256), 0, stream>>>(xb, WkT, sm + SM_BK, Kt, nullptr, nullptr);
    gemm_bt<1><<<dim3(32, 4), dim3(256), 0, stream>>>(xb, WvT, sm + SM_BV, VTb, nullptr, nullptr);
    gemm_bt<4><<<dim3(288, 4), dim3(256), 0, stream>>>((const bf16*)queries, WqT, sm + SM_BQ, Qf, flag, Qc);

    for (int b0 = 0; b0 < NB; b0 += CB) {
        gemm_s<<<dim3(18, 2, CB*8), dim3(256), 0, stream>>>(Qf, Kt, Sb, b0);
        mix_softmax<<<dim3(72, CB), dim3(256), 0, stream>>>(Sb, twf, ss, b0);
        gemm_pv<<<dim3(18, CB*8), dim3(256), 0, stream>>>(Sb, VTb, Ub, b0);
    }

    scale_wot<<<dim3(2048), dim3(256), 0, stream>>>(WoT, ss, WoTp);
    gemm_bt<2><<<dim3(288, 4), dim3(256), 0, stream>>>(Ub, WoTp, sm + SM_BO, (bf16*)d_out, flag, nullptr);
}